// Round 11
// baseline (263.013 us; speedup 1.0000x reference)
//
#include <hip/hip_runtime.h>
#include <hip/hip_bf16.h>
#include <cstdint>

#define BB 64
#define TT 200
#define KN 2000
#define VV 128

typedef __attribute__((ext_vector_type(8))) short bf16x8;
typedef __attribute__((ext_vector_type(4))) float f32x4;
typedef _Float16 half8 __attribute__((ext_vector_type(8)));

// ws layout (floats): pd[384]@0, pr[384]@384, uc[128]@768, ud[128]@896, ur[128]@1024

__device__ __forceinline__ float sigm(float x) { return 1.f / (1.f + __expf(-x)); }
__device__ __forceinline__ float tanh_f(float x) {
    float e = __expf(2.f * x);
    return (e - 1.f) / (e + 1.f);
}

// lgkmcnt-only barrier (GRU loop): orders LDS produce->consume without draining
// the in-flight global h_out stores.
__device__ __forceinline__ void soft_barrier() {
    asm volatile("s_waitcnt lgkmcnt(0)" ::: "memory");
    __builtin_amdgcn_s_barrier();
    __builtin_amdgcn_sched_barrier(0);
}

// ---------------- precompute: small projection vectors ----------
__global__ void pre_kernel(const float* __restrict__ v_d, const float* __restrict__ v_r,
                           const float* __restrict__ v_c, const float* __restrict__ W_ih,
                           const float* __restrict__ W2a, float* __restrict__ ws)
{
    int g = blockIdx.x * 256 + threadIdx.x;   // grid 2 x 256 = 512 threads
    float* pd = ws;
    float* pr = ws + 384;
    float* uc = ws + 768;
    float* ud = ws + 896;
    float* ur = ws + 1024;
    if (g < 384) {
        float a = 0.f, b = 0.f;
        for (int k = 0; k < VV; ++k) {
            a = fmaf(W_ih[g * 256 + k], v_d[k], a);
            b = fmaf(W_ih[g * 256 + VV + k], v_r[k], b);
        }
        pd[g] = a; pr[g] = b;
    }
    if (g < VV) {
        float a = 0.f, b = 0.f, c = 0.f;
        for (int k = 0; k < VV; ++k) {
            a = fmaf(W2a[g * 384 + k], v_c[k], a);
            b = fmaf(W2a[g * 384 + VV + k], v_d[k], b);
            c = fmaf(W2a[g * 384 + 2 * VV + k], v_r[k], c);
        }
        uc[g] = a; ud[g] = b; ur[g] = c;
    }
}

__device__ __forceinline__ half8 load_cvt8h(const float* p) {
    float4 a = *(const float4*)p;
    float4 c = *(const float4*)(p + 4);
    half8 r;
    r[0] = (_Float16)a.x; r[1] = (_Float16)a.y; r[2] = (_Float16)a.z; r[3] = (_Float16)a.w;
    r[4] = (_Float16)c.x; r[5] = (_Float16)c.y; r[6] = (_Float16)c.z; r[7] = (_Float16)c.w;
    return r;
}

// ---------------- fused: blocks 0-3 GRU (16 rows, MFMA), blocks 4-67 mem scan --
// r10 lesson: GRU path ~45us (MfmaUtil-derived); the 227us pole was the mem
// path's per-step {dependent C read -> shfl chain -> 2 barriers -> conflicted
// stream}. New mem structure: phase1 barrier-free wave0 scan (C[c(t+1)] prefetch
// + select kills the LDS read latency), one barrier, phase2 all-wave parallel
// reconstruction with uniform-broadcast LDS reads + coalesced float4 stores.
__global__ __launch_bounds__(512, 1) void fused_kernel(
    const int* __restrict__ c_seq, const int* __restrict__ d_seq,
    const float* __restrict__ r_seq, const float* __restrict__ D_emb,
    const float* __restrict__ Whh, const float* __restrict__ bih,
    const float* __restrict__ bhh, const float* __restrict__ W2b,
    const float* __restrict__ b2a, const float* __restrict__ b2b,
    const float* __restrict__ ws, float* __restrict__ C_out,
    float* __restrict__ h_out)
{
    __shared__ __align__(16) _Float16 H_half[16 * 136];   // padded rows: 136 halves
    __shared__ float gam16[TT * 16], r16[TT * 16];        // [t][row]
    __shared__ __align__(16) float C[KN];
    __shared__ float gam_row[TT], r_row[TT], n_row[TT];
    __shared__ int c_row[TT + 1];

    int tid = threadIdx.x;

    if (blockIdx.x < 4) {
        // ================= GRU path: 16 batch rows =================
        int b0 = blockIdx.x * 16;
        const float* pd = ws;
        const float* pr = ws + 384;

        for (int i = tid; i < TT * 16; i += 512) {
            int t = i >> 4, r = i & 15;
            gam16[i] = D_emb[d_seq[(b0 + r) * TT + t]];
            r16[i] = r_seq[(b0 + r) * TT + t];
        }
        for (int i = tid; i < 16 * 136; i += 512) H_half[i] = (_Float16)0.f;

        int wid = tid >> 6, l = tid & 63;
        int cl = l & 15, gq = l >> 4;
        int nn = wid * 16 + cl;      // output col (n index 0..127)
        int r0 = gq * 4;             // first of 4 batch rows this lane owns

        // B-fragments: 12 frags = 48 VGPRs, resident (r9: FETCH 590KB confirmed)
        const float* wr = Whh + (size_t)nn * VV + gq * 8;
        const float* wz = Whh + (size_t)(nn + 128) * VV + gq * 8;
        const float* wn = Whh + (size_t)(nn + 256) * VV + gq * 8;
        half8 br0 = load_cvt8h(wr),      br1 = load_cvt8h(wr + 32),
              br2 = load_cvt8h(wr + 64), br3 = load_cvt8h(wr + 96);
        half8 bz0 = load_cvt8h(wz),      bz1 = load_cvt8h(wz + 32),
              bz2 = load_cvt8h(wz + 64), bz3 = load_cvt8h(wz + 96);
        half8 bn0 = load_cvt8h(wn),      bn1 = load_cvt8h(wn + 32),
              bn2 = load_cvt8h(wn + 64), bn3 = load_cvt8h(wn + 96);

        // per-lane gi fold scalars (n fixed per lane)
        float gr_pd = pd[nn],        gr_pr = pr[nn],        gr_b = bih[nn] + bhh[nn];
        float gz_pd = pd[nn + 128],  gz_pr = pr[nn + 128],  gz_b = bih[nn + 128] + bhh[nn + 128];
        float gn_pd = pd[nn + 256],  gn_pr = pr[nn + 256],  gn_b = bih[nn + 256];
        float gn_bh = bhh[nn + 256];

        float h0 = 0.f, h1 = 0.f, h2 = 0.f, h3 = 0.f;
        __syncthreads();   // setup barrier

        for (int t = 0; t < TT; ++t) {
            asm volatile("" : "+v"(br0), "+v"(br1), "+v"(br2), "+v"(br3),
                              "+v"(bz0), "+v"(bz1), "+v"(bz2), "+v"(bz3),
                              "+v"(bn0), "+v"(bn1), "+v"(bn2), "+v"(bn3));
            const int ab = cl * 136 + gq * 8;
            half8 a0 = *(const half8*)&H_half[ab];
            half8 a1 = *(const half8*)&H_half[ab + 32];
            half8 a2 = *(const half8*)&H_half[ab + 64];
            half8 a3 = *(const half8*)&H_half[ab + 96];

            f32x4 accr = {0.f, 0.f, 0.f, 0.f};
            f32x4 accz = {0.f, 0.f, 0.f, 0.f};
            f32x4 accn = {0.f, 0.f, 0.f, 0.f};
            accr = __builtin_amdgcn_mfma_f32_16x16x32_f16(a0, br0, accr, 0, 0, 0);
            accr = __builtin_amdgcn_mfma_f32_16x16x32_f16(a1, br1, accr, 0, 0, 0);
            accr = __builtin_amdgcn_mfma_f32_16x16x32_f16(a2, br2, accr, 0, 0, 0);
            accr = __builtin_amdgcn_mfma_f32_16x16x32_f16(a3, br3, accr, 0, 0, 0);
            accz = __builtin_amdgcn_mfma_f32_16x16x32_f16(a0, bz0, accz, 0, 0, 0);
            accz = __builtin_amdgcn_mfma_f32_16x16x32_f16(a1, bz1, accz, 0, 0, 0);
            accz = __builtin_amdgcn_mfma_f32_16x16x32_f16(a2, bz2, accz, 0, 0, 0);
            accz = __builtin_amdgcn_mfma_f32_16x16x32_f16(a3, bz3, accz, 0, 0, 0);
            accn = __builtin_amdgcn_mfma_f32_16x16x32_f16(a0, bn0, accn, 0, 0, 0);
            accn = __builtin_amdgcn_mfma_f32_16x16x32_f16(a1, bn1, accn, 0, 0, 0);
            accn = __builtin_amdgcn_mfma_f32_16x16x32_f16(a2, bn2, accn, 0, 0, 0);
            accn = __builtin_amdgcn_mfma_f32_16x16x32_f16(a3, bn3, accn, 0, 0, 0);

            #define GATE(i, hvar) { \
                float g = gam16[t * 16 + r0 + i], rr = r16[t * 16 + r0 + i]; \
                float rg = sigm(accr[i] + fmaf(g, gr_pd, fmaf(rr, gr_pr, gr_b))); \
                float zg = sigm(accz[i] + fmaf(g, gz_pd, fmaf(rr, gz_pr, gz_b))); \
                float gin = fmaf(g, gn_pd, fmaf(rr, gn_pr, gn_b)); \
                float ng = tanh_f(fmaf(rg, accn[i] + gn_bh, gin)); \
                hvar = fmaf(1.f - zg, ng, zg * hvar); \
                h_out[((size_t)(b0 + r0 + i) * TT + t) * VV + nn] = hvar; \
                H_half[(r0 + i) * 136 + nn] = (_Float16)hvar; }
            GATE(0, h0) GATE(1, h1) GATE(2, h2) GATE(3, h3)
            #undef GATE
            soft_barrier();   // LDS H_half visibility; h_out stays in flight
        }
    } else {
        // ================= memory-scan path: 2 phases =================
        int b = blockIdx.x - 4;
        const float* uc = ws + 768;
        const float* ud = ws + 896;
        const float* ur = ws + 1024;
        for (int i = tid; i < KN; i += 512) C[i] = 0.f;
        if (tid < TT) {
            gam_row[tid] = D_emb[d_seq[b * TT + tid]];
            r_row[tid] = r_seq[b * TT + tid];
            c_row[tid] = c_seq[b * TT + tid];
        }
        if (tid == 0) c_row[TT] = 0;
        __syncthreads();

        // ---- phase 1: wave0 scans; C[c(t+1)] prefetch + select breaks the
        //      dependent-LDS-read chain (earlier writers precede the prefetch
        //      in program order; the same-step write is exactly the select) ----
        if (tid < 64) {
            int l = tid;
            float uc0 = uc[l], uc1 = uc[l + 64];
            float ud0 = ud[l], ud1 = ud[l + 64];
            float ur0 = ur[l], ur1 = ur[l + 64];
            float ba0 = b2a[l], ba1 = b2a[l + 64];
            float wb0 = W2b[l], wb1 = W2b[l + 64];
            float bb = b2b[0];
            float beta = 0.f;              // C starts all-zero
            int ct = c_row[0];
            for (int t = 0; t < TT; ++t) {
                int ct1 = c_row[t + 1];
                float cpref = C[ct1];      // early, independent issue
                float g = gam_row[t], rr = r_row[t];
                float hh0 = fmaxf(fmaf(beta, uc0, fmaf(g, ud0, fmaf(rr, ur0, ba0))), 0.f);
                float hh1 = fmaxf(fmaf(beta, uc1, fmaf(g, ud1, fmaf(rr, ur1, ba1))), 0.f);
                float p = fmaf(hh0, wb0, hh1 * wb1);
                #pragma unroll
                for (int m = 32; m > 0; m >>= 1) p += __shfl_xor(p, m);
                float nc = p + bb;
                if (l == 0) { C[ct] = nc; n_row[t] = nc; }
                beta = (ct1 == ct) ? nc : cpref;
                ct = ct1;
            }
        }
        __syncthreads();

        // ---- phase 2: all 8 waves reconstruct C_out; uniform-broadcast LDS
        //      reads, coalesced float4 stores, no barriers ----
        int k0 = tid * 4;
        if (k0 < KN) {
            float4 cur = {0.f, 0.f, 0.f, 0.f};
            float* cop = C_out + (size_t)b * TT * KN + k0;
            for (int t = 0; t < TT; ++t) {
                int c = c_row[t];
                unsigned d = (unsigned)(c - k0);
                if (d < 4u) {
                    float v = n_row[t];
                    cur.x = (d == 0u) ? v : cur.x;
                    cur.y = (d == 1u) ? v : cur.y;
                    cur.z = (d == 2u) ? v : cur.z;
                    cur.w = (d == 3u) ? v : cur.w;
                }
                *(float4*)(cop + (size_t)t * KN) = cur;
            }
        }
    }
}

// ---------------- alpha head: bf16 MFMA, fragments loaded straight from global -
__device__ __forceinline__ short f2bf(float f) {
    uint32_t u = __float_as_uint(f);
    u = (u + 0x7FFFu + ((u >> 16) & 1u)) >> 16;
    return (short)u;
}
__device__ __forceinline__ bf16x8 load_cvt8(const float* p) {
    float4 a = *(const float4*)p;
    float4 c = *(const float4*)(p + 4);
    bf16x8 r;
    r[0] = f2bf(a.x); r[1] = f2bf(a.y); r[2] = f2bf(a.z); r[3] = f2bf(a.w);
    r[4] = f2bf(c.x); r[5] = f2bf(c.y); r[6] = f2bf(c.z); r[7] = f2bf(c.w);
    return r;
}

__global__ void alpha_kernel(const float* __restrict__ h_seq, const float* __restrict__ W1a,
                             const float* __restrict__ b1a, const float* __restrict__ W1b,
                             const float* __restrict__ b1b, float* __restrict__ alpha)
{
    int wave = threadIdx.x >> 6;
    int lane = threadIdx.x & 63;
    int tile = blockIdx.x * 4 + wave;  // 800 tiles of 16 rows
    int rowbase = tile * 16;
    int rl = lane & 15, g = lane >> 4;
    const float* hp = h_seq + (size_t)(rowbase + rl) * VV + g * 8;
    bf16x8 a0 = load_cvt8(hp);
    bf16x8 a1 = load_cvt8(hp + 32);
    bf16x8 a2 = load_cvt8(hp + 64);
    bf16x8 a3 = load_cvt8(hp + 96);
    float p0 = 0.f, p1 = 0.f, p2 = 0.f, p3 = 0.f;
    float bb = b1b[0];
    #pragma unroll
    for (int jt = 0; jt < 8; ++jt) {
        int j = jt * 16 + rl;
        const float* wp = W1a + (size_t)j * VV + g * 8;
        f32x4 acc = {0.f, 0.f, 0.f, 0.f};
        acc = __builtin_amdgcn_mfma_f32_16x16x32_bf16(a0, load_cvt8(wp), acc, 0, 0, 0);
        acc = __builtin_amdgcn_mfma_f32_16x16x32_bf16(a1, load_cvt8(wp + 32), acc, 0, 0, 0);
        acc = __builtin_amdgcn_mfma_f32_16x16x32_bf16(a2, load_cvt8(wp + 64), acc, 0, 0, 0);
        acc = __builtin_amdgcn_mfma_f32_16x16x32_bf16(a3, load_cvt8(wp + 96), acc, 0, 0, 0);
        float bj = b1a[j], wj = W1b[j];
        p0 += fmaxf(acc[0] + bj, 0.f) * wj;
        p1 += fmaxf(acc[1] + bj, 0.f) * wj;
        p2 += fmaxf(acc[2] + bj, 0.f) * wj;
        p3 += fmaxf(acc[3] + bj, 0.f) * wj;
    }
    #pragma unroll
    for (int m = 1; m < 16; m <<= 1) {
        p0 += __shfl_xor(p0, m);
        p1 += __shfl_xor(p1, m);
        p2 += __shfl_xor(p2, m);
        p3 += __shfl_xor(p3, m);
    }
    if (rl == 0) {
        alpha[rowbase + g * 4 + 0] = p0 + bb;
        alpha[rowbase + g * 4 + 1] = p1 + bb;
        alpha[rowbase + g * 4 + 2] = p2 + bb;
        alpha[rowbase + g * 4 + 3] = p3 + bb;
    }
}

extern "C" void kernel_launch(void* const* d_in, const int* in_sizes, int n_in,
                              void* d_out, int out_size, void* d_ws, size_t ws_size,
                              hipStream_t stream)
{
    const int*   c_seq = (const int*)d_in[0];
    const int*   d_seq = (const int*)d_in[1];
    const float* r_seq = (const float*)d_in[2];
    const float* D_emb = (const float*)d_in[3];
    const float* v_d   = (const float*)d_in[4];
    const float* v_r   = (const float*)d_in[5];
    const float* v_c   = (const float*)d_in[6];
    const float* W_ih  = (const float*)d_in[7];
    const float* W_hh  = (const float*)d_in[8];
    const float* b_ih  = (const float*)d_in[9];
    const float* b_hh  = (const float*)d_in[10];
    const float* W1a   = (const float*)d_in[11];
    const float* b1a   = (const float*)d_in[12];
    const float* W1b   = (const float*)d_in[13];
    const float* b1b   = (const float*)d_in[14];
    const float* W2a   = (const float*)d_in[15];
    const float* b2a   = (const float*)d_in[16];
    const float* W2b   = (const float*)d_in[17];
    const float* b2b   = (const float*)d_in[18];

    float* out   = (float*)d_out;
    float* alpha = out;                       // 12800
    float* h_seq = out + 12800;               // 1,638,400
    float* C_out = out + 12800 + 1638400;     // 25,600,000
    float* ws    = (float*)d_ws;

    hipLaunchKernelGGL(pre_kernel, dim3(2), dim3(256), 0, stream,
                       v_d, v_r, v_c, W_ih, W2a, ws);
    hipLaunchKernelGGL(fused_kernel, dim3(4 + BB), dim3(512), 0, stream,
                       c_seq, d_seq, r_seq, D_emb, W_hh, b_ih, b_hh,
                       W2b, b2a, b2b, ws, C_out, h_seq);
    hipLaunchKernelGGL(alpha_kernel, dim3(200), dim3(256), 0, stream,
                       h_seq, W1a, b1a, W1b, b1b, alpha);
}

// Round 13
// 179.296 us; speedup vs baseline: 1.4669x; 1.4669x over previous
//
#include <hip/hip_runtime.h>
#include <hip/hip_bf16.h>
#include <cstdint>

#define BB 64
#define TT 200
#define KN 2000
#define VV 128

typedef __attribute__((ext_vector_type(8))) short bf16x8;
typedef __attribute__((ext_vector_type(4))) float f32x4;
typedef _Float16 half8 __attribute__((ext_vector_type(8)));

// ws layout (floats): pd[384]@0, pr[384]@384, uc[128]@768, ud[128]@896, ur[128]@1024

// r11 lesson: gate-phase IEEE divisions (12/thread/step) sat on the recurrence
// chain. rcp-based forms (~1ulp) are far below the 4e-3 tolerance.
__device__ __forceinline__ float sigm(float x) {
    return __builtin_amdgcn_rcpf(1.f + __expf(-x));
}
__device__ __forceinline__ float tanh_f(float x) {
    float e = __expf(2.f * x);
    return 1.f - 2.f * __builtin_amdgcn_rcpf(e + 1.f);
}

// lgkmcnt-only barrier: orders LDS produce->consume without draining in-flight
// global stores (h_out). sched_barrier keeps MFMA from hoisting past the wait.
__device__ __forceinline__ void soft_barrier() {
    asm volatile("s_waitcnt lgkmcnt(0)" ::: "memory");
    __builtin_amdgcn_s_barrier();
    __builtin_amdgcn_sched_barrier(0);
}

// ---------------- precompute: small projection vectors ----------
__global__ void pre_kernel(const float* __restrict__ v_d, const float* __restrict__ v_r,
                           const float* __restrict__ v_c, const float* __restrict__ W_ih,
                           const float* __restrict__ W2a, float* __restrict__ ws)
{
    int g = blockIdx.x * 256 + threadIdx.x;   // grid 2 x 256 = 512 threads
    float* pd = ws;
    float* pr = ws + 384;
    float* uc = ws + 768;
    float* ud = ws + 896;
    float* ur = ws + 1024;
    if (g < 384) {
        float a = 0.f, b = 0.f;
        for (int k = 0; k < VV; ++k) {
            a = fmaf(W_ih[g * 256 + k], v_d[k], a);
            b = fmaf(W_ih[g * 256 + VV + k], v_r[k], b);
        }
        pd[g] = a; pr[g] = b;
    }
    if (g < VV) {
        float a = 0.f, b = 0.f, c = 0.f;
        for (int k = 0; k < VV; ++k) {
            a = fmaf(W2a[g * 384 + k], v_c[k], a);
            b = fmaf(W2a[g * 384 + VV + k], v_d[k], b);
            c = fmaf(W2a[g * 384 + 2 * VV + k], v_r[k], c);
        }
        uc[g] = a; ud[g] = b; ur[g] = c;
    }
}

__device__ __forceinline__ half8 load_cvt8h(const float* p) {
    float4 a = *(const float4*)p;
    float4 c = *(const float4*)(p + 4);
    half8 r;
    r[0] = (_Float16)a.x; r[1] = (_Float16)a.y; r[2] = (_Float16)a.z; r[3] = (_Float16)a.w;
    r[4] = (_Float16)c.x; r[5] = (_Float16)c.y; r[6] = (_Float16)c.z; r[7] = (_Float16)c.w;
    return r;
}

// ---------------- fused: blocks 0-3 GRU (16 rows, MFMA), blocks 4-67 mem scan --
// GRU gate phase reworked (r11): rcp activations, gi folded into MFMA C-in
// (overlaps the A-frag ds_read latency), gam/r as float4 LDS reads.
__global__ __launch_bounds__(512, 1) void fused_kernel(
    const int* __restrict__ c_seq, const int* __restrict__ d_seq,
    const float* __restrict__ r_seq, const float* __restrict__ D_emb,
    const float* __restrict__ Whh, const float* __restrict__ bih,
    const float* __restrict__ bhh, const float* __restrict__ W2b,
    const float* __restrict__ b2a, const float* __restrict__ b2b,
    const float* __restrict__ ws, float* __restrict__ C_out,
    float* __restrict__ h_out)
{
    __shared__ __align__(16) _Float16 H_half[16 * 136];   // padded rows: 136 halves
    __shared__ __align__(16) float gam16[TT * 16], r16[TT * 16];  // [t][row]
    __shared__ __align__(16) float C[KN];
    __shared__ float gam_row[TT], r_row[TT], n_row[TT];
    __shared__ int c_row[TT + 1];

    int tid = threadIdx.x;

    if (blockIdx.x < 4) {
        // ================= GRU path: 16 batch rows =================
        int b0 = blockIdx.x * 16;
        const float* pd = ws;
        const float* pr = ws + 384;

        for (int i = tid; i < TT * 16; i += 512) {
            int t = i >> 4, r = i & 15;
            gam16[i] = D_emb[d_seq[(b0 + r) * TT + t]];
            r16[i] = r_seq[(b0 + r) * TT + t];
        }
        for (int i = tid; i < 16 * 136; i += 512) H_half[i] = (_Float16)0.f;

        int wid = tid >> 6, l = tid & 63;
        int cl = l & 15, gq = l >> 4;
        int nn = wid * 16 + cl;      // output col (n index 0..127)
        int r0 = gq * 4;             // first of 4 batch rows this lane owns

        // B-fragments: 12 frags = 48 VGPRs, resident (r9: FETCH 590KB confirmed)
        const float* wr = Whh + (size_t)nn * VV + gq * 8;
        const float* wz = Whh + (size_t)(nn + 128) * VV + gq * 8;
        const float* wn = Whh + (size_t)(nn + 256) * VV + gq * 8;
        half8 br0 = load_cvt8h(wr),      br1 = load_cvt8h(wr + 32),
              br2 = load_cvt8h(wr + 64), br3 = load_cvt8h(wr + 96);
        half8 bz0 = load_cvt8h(wz),      bz1 = load_cvt8h(wz + 32),
              bz2 = load_cvt8h(wz + 64), bz3 = load_cvt8h(wz + 96);
        half8 bn0 = load_cvt8h(wn),      bn1 = load_cvt8h(wn + 32),
              bn2 = load_cvt8h(wn + 64), bn3 = load_cvt8h(wn + 96);

        // per-lane gi fold scalars (n fixed per lane)
        float gr_pd = pd[nn],        gr_pr = pr[nn],        gr_b = bih[nn] + bhh[nn];
        float gz_pd = pd[nn + 128],  gz_pr = pr[nn + 128],  gz_b = bih[nn + 128] + bhh[nn + 128];
        float gn_pd = pd[nn + 256],  gn_pr = pr[nn + 256],  gn_b = bih[nn + 256];
        float gn_bh = bhh[nn + 256];

        float h0 = 0.f, h1 = 0.f, h2 = 0.f, h3 = 0.f;
        __syncthreads();   // setup barrier

        for (int t = 0; t < TT; ++t) {
            asm volatile("" : "+v"(br0), "+v"(br1), "+v"(br2), "+v"(br3),
                              "+v"(bz0), "+v"(bz1), "+v"(bz2), "+v"(bz3),
                              "+v"(bn0), "+v"(bn1), "+v"(bn2), "+v"(bn3));
            // A-fragments + per-step scalars (b128 reads; fold overlaps latency)
            const int ab = cl * 136 + gq * 8;
            half8 a0 = *(const half8*)&H_half[ab];
            half8 a1 = *(const half8*)&H_half[ab + 32];
            half8 a2 = *(const half8*)&H_half[ab + 64];
            half8 a3 = *(const half8*)&H_half[ab + 96];
            float4 g4 = *(const float4*)&gam16[t * 16 + r0];
            float4 q4 = *(const float4*)&r16[t * 16 + r0];

            // gi fold as MFMA C-in: accr/accz = gi_{r,z}+b_ih+b_hh; accn = bhh_n
            f32x4 accr, accz, accn, gin;
            accr[0] = fmaf(g4.x, gr_pd, fmaf(q4.x, gr_pr, gr_b));
            accr[1] = fmaf(g4.y, gr_pd, fmaf(q4.y, gr_pr, gr_b));
            accr[2] = fmaf(g4.z, gr_pd, fmaf(q4.z, gr_pr, gr_b));
            accr[3] = fmaf(g4.w, gr_pd, fmaf(q4.w, gr_pr, gr_b));
            accz[0] = fmaf(g4.x, gz_pd, fmaf(q4.x, gz_pr, gz_b));
            accz[1] = fmaf(g4.y, gz_pd, fmaf(q4.y, gz_pr, gz_b));
            accz[2] = fmaf(g4.z, gz_pd, fmaf(q4.z, gz_pr, gz_b));
            accz[3] = fmaf(g4.w, gz_pd, fmaf(q4.w, gz_pr, gz_b));
            accn[0] = gn_bh; accn[1] = gn_bh; accn[2] = gn_bh; accn[3] = gn_bh;
            gin[0] = fmaf(g4.x, gn_pd, fmaf(q4.x, gn_pr, gn_b));
            gin[1] = fmaf(g4.y, gn_pd, fmaf(q4.y, gn_pr, gn_b));
            gin[2] = fmaf(g4.z, gn_pd, fmaf(q4.z, gn_pr, gn_b));
            gin[3] = fmaf(g4.w, gn_pd, fmaf(q4.w, gn_pr, gn_b));

            accr = __builtin_amdgcn_mfma_f32_16x16x32_f16(a0, br0, accr, 0, 0, 0);
            accr = __builtin_amdgcn_mfma_f32_16x16x32_f16(a1, br1, accr, 0, 0, 0);
            accr = __builtin_amdgcn_mfma_f32_16x16x32_f16(a2, br2, accr, 0, 0, 0);
            accr = __builtin_amdgcn_mfma_f32_16x16x32_f16(a3, br3, accr, 0, 0, 0);
            accz = __builtin_amdgcn_mfma_f32_16x16x32_f16(a0, bz0, accz, 0, 0, 0);
            accz = __builtin_amdgcn_mfma_f32_16x16x32_f16(a1, bz1, accz, 0, 0, 0);
            accz = __builtin_amdgcn_mfma_f32_16x16x32_f16(a2, bz2, accz, 0, 0, 0);
            accz = __builtin_amdgcn_mfma_f32_16x16x32_f16(a3, bz3, accz, 0, 0, 0);
            accn = __builtin_amdgcn_mfma_f32_16x16x32_f16(a0, bn0, accn, 0, 0, 0);
            accn = __builtin_amdgcn_mfma_f32_16x16x32_f16(a1, bn1, accn, 0, 0, 0);
            accn = __builtin_amdgcn_mfma_f32_16x16x32_f16(a2, bn2, accn, 0, 0, 0);
            accn = __builtin_amdgcn_mfma_f32_16x16x32_f16(a3, bn3, accn, 0, 0, 0);

            // gates: acc[i] belongs to (row=r0+i, col=nn) -- lane-local
            #define GATE(i, hvar) { \
                float rg = sigm(accr[i]); \
                float zg = sigm(accz[i]); \
                float ng = tanh_f(fmaf(rg, accn[i], gin[i])); \
                hvar = fmaf(1.f - zg, ng, zg * hvar); \
                h_out[((size_t)(b0 + r0 + i) * TT + t) * VV + nn] = hvar; \
                H_half[(r0 + i) * 136 + nn] = (_Float16)hvar; }
            GATE(0, h0) GATE(1, h1) GATE(2, h2) GATE(3, h3)
            #undef GATE
            soft_barrier();   // LDS H_half visibility; h_out stays in flight
        }
    } else {
        // ================= memory-scan path: 2 phases =================
        int b = blockIdx.x - 4;
        const float* uc = ws + 768;
        const float* ud = ws + 896;
        const float* ur = ws + 1024;
        for (int i = tid; i < KN; i += 512) C[i] = 0.f;
        if (tid < TT) {
            gam_row[tid] = D_emb[d_seq[b * TT + tid]];
            r_row[tid] = r_seq[b * TT + tid];
            c_row[tid] = c_seq[b * TT + tid];
        }
        if (tid == 0) c_row[TT] = 0;
        __syncthreads();

        // ---- phase 1: wave0 scans; C[c(t+1)] prefetch + select breaks the
        //      dependent-LDS-read chain ----
        if (tid < 64) {
            int l = tid;
            float uc0 = uc[l], uc1 = uc[l + 64];
            float ud0 = ud[l], ud1 = ud[l + 64];
            float ur0 = ur[l], ur1 = ur[l + 64];
            float ba0 = b2a[l], ba1 = b2a[l + 64];
            float wb0 = W2b[l], wb1 = W2b[l + 64];
            float bb = b2b[0];
            float beta = 0.f;              // C starts all-zero
            int ct = c_row[0];
            for (int t = 0; t < TT; ++t) {
                int ct1 = c_row[t + 1];
                float cpref = C[ct1];      // early, independent issue
                float g = gam_row[t], rr = r_row[t];
                float hh0 = fmaxf(fmaf(beta, uc0, fmaf(g, ud0, fmaf(rr, ur0, ba0))), 0.f);
                float hh1 = fmaxf(fmaf(beta, uc1, fmaf(g, ud1, fmaf(rr, ur1, ba1))), 0.f);
                float p = fmaf(hh0, wb0, hh1 * wb1);
                #pragma unroll
                for (int m = 32; m > 0; m >>= 1) p += __shfl_xor(p, m);
                float nc = p + bb;
                if (l == 0) { C[ct] = nc; n_row[t] = nc; }
                beta = (ct1 == ct) ? nc : cpref;
                ct = ct1;
            }
        }
        __syncthreads();

        // ---- phase 2: all 8 waves reconstruct C_out; uniform-broadcast LDS
        //      reads, coalesced float4 stores, no barriers ----
        int k0 = tid * 4;
        if (k0 < KN) {
            float4 cur = {0.f, 0.f, 0.f, 0.f};
            float* cop = C_out + (size_t)b * TT * KN + k0;
            for (int t = 0; t < TT; ++t) {
                int c = c_row[t];
                unsigned d = (unsigned)(c - k0);
                if (d < 4u) {
                    float v = n_row[t];
                    cur.x = (d == 0u) ? v : cur.x;
                    cur.y = (d == 1u) ? v : cur.y;
                    cur.z = (d == 2u) ? v : cur.z;
                    cur.w = (d == 3u) ? v : cur.w;
                }
                *(float4*)(cop + (size_t)t * KN) = cur;
            }
        }
    }
}

// ---------------- alpha head: bf16 MFMA, fragments loaded straight from global -
__device__ __forceinline__ short f2bf(float f) {
    uint32_t u = __float_as_uint(f);
    u = (u + 0x7FFFu + ((u >> 16) & 1u)) >> 16;
    return (short)u;
}
__device__ __forceinline__ bf16x8 load_cvt8(const float* p) {
    float4 a = *(const float4*)p;
    float4 c = *(const float4*)(p + 4);
    bf16x8 r;
    r[0] = f2bf(a.x); r[1] = f2bf(a.y); r[2] = f2bf(a.z); r[3] = f2bf(a.w);
    r[4] = f2bf(c.x); r[5] = f2bf(c.y); r[6] = f2bf(c.z); r[7] = f2bf(c.w);
    return r;
}

__global__ void alpha_kernel(const float* __restrict__ h_seq, const float* __restrict__ W1a,
                             const float* __restrict__ b1a, const float* __restrict__ W1b,
                             const float* __restrict__ b1b, float* __restrict__ alpha)
{
    int wave = threadIdx.x >> 6;
    int lane = threadIdx.x & 63;
    int tile = blockIdx.x * 4 + wave;  // 800 tiles of 16 rows
    int rowbase = tile * 16;
    int rl = lane & 15, g = lane >> 4;
    const float* hp = h_seq + (size_t)(rowbase + rl) * VV + g * 8;
    bf16x8 a0 = load_cvt8(hp);
    bf16x8 a1 = load_cvt8(hp + 32);
    bf16x8 a2 = load_cvt8(hp + 64);
    bf16x8 a3 = load_cvt8(hp + 96);
    float p0 = 0.f, p1 = 0.f, p2 = 0.f, p3 = 0.f;
    float bb = b1b[0];
    #pragma unroll
    for (int jt = 0; jt < 8; ++jt) {
        int j = jt * 16 + rl;
        const float* wp = W1a + (size_t)j * VV + g * 8;
        f32x4 acc = {0.f, 0.f, 0.f, 0.f};
        acc = __builtin_amdgcn_mfma_f32_16x16x32_bf16(a0, load_cvt8(wp), acc, 0, 0, 0);
        acc = __builtin_amdgcn_mfma_f32_16x16x32_bf16(a1, load_cvt8(wp + 32), acc, 0, 0, 0);
        acc = __builtin_amdgcn_mfma_f32_16x16x32_bf16(a2, load_cvt8(wp + 64), acc, 0, 0, 0);
        acc = __builtin_amdgcn_mfma_f32_16x16x32_bf16(a3, load_cvt8(wp + 96), acc, 0, 0, 0);
        float bj = b1a[j], wj = W1b[j];
        p0 += fmaxf(acc[0] + bj, 0.f) * wj;
        p1 += fmaxf(acc[1] + bj, 0.f) * wj;
        p2 += fmaxf(acc[2] + bj, 0.f) * wj;
        p3 += fmaxf(acc[3] + bj, 0.f) * wj;
    }
    #pragma unroll
    for (int m = 1; m < 16; m <<= 1) {
        p0 += __shfl_xor(p0, m);
        p1 += __shfl_xor(p1, m);
        p2 += __shfl_xor(p2, m);
        p3 += __shfl_xor(p3, m);
    }
    if (rl == 0) {
        alpha[rowbase + g * 4 + 0] = p0 + bb;
        alpha[rowbase + g * 4 + 1] = p1 + bb;
        alpha[rowbase + g * 4 + 2] = p2 + bb;
        alpha[rowbase + g * 4 + 3] = p3 + bb;
    }
}

extern "C" void kernel_launch(void* const* d_in, const int* in_sizes, int n_in,
                              void* d_out, int out_size, void* d_ws, size_t ws_size,
                              hipStream_t stream)
{
    const int*   c_seq = (const int*)d_in[0];
    const int*   d_seq = (const int*)d_in[1];
    const float* r_seq = (const float*)d_in[2];
    const float* D_emb = (const float*)d_in[3];
    const float* v_d   = (const float*)d_in[4];
    const float* v_r   = (const float*)d_in[5];
    const float* v_c   = (const float*)d_in[6];
    const float* W_ih  = (const float*)d_in[7];
    const float* W_hh  = (const float*)d_in[8];
    const float* b_ih  = (const float*)d_in[9];
    const float* b_hh  = (const float*)d_in[10];
    const float* W1a   = (const float*)d_in[11];
    const float* b1a   = (const float*)d_in[12];
    const float* W1b   = (const float*)d_in[13];
    const float* b1b   = (const float*)d_in[14];
    const float* W2a   = (const float*)d_in[15];
    const float* b2a   = (const float*)d_in[16];
    const float* W2b   = (const float*)d_in[17];
    const float* b2b   = (const float*)d_in[18];

    float* out   = (float*)d_out;
    float* alpha = out;                       // 12800
    float* h_seq = out + 12800;               // 1,638,400
    float* C_out = out + 12800 + 1638400;     // 25,600,000
    float* ws    = (float*)d_ws;

    hipLaunchKernelGGL(pre_kernel, dim3(2), dim3(256), 0, stream,
                       v_d, v_r, v_c, W_ih, W2a, ws);
    hipLaunchKernelGGL(fused_kernel, dim3(4 + BB), dim3(512), 0, stream,
                       c_seq, d_seq, r_seq, D_emb, W_hh, b_ih, b_hh,
                       W2b, b2a, b2b, ws, C_out, h_seq);
    hipLaunchKernelGGL(alpha_kernel, dim3(200), dim3(256), 0, stream,
                       h_seq, W1a, b1a, W1b, b1b, alpha);
}

// Round 15
// 142.794 us; speedup vs baseline: 1.8419x; 1.2556x over previous
//
#include <hip/hip_runtime.h>
#include <hip/hip_bf16.h>
#include <cstdint>

#define BB 64
#define TT 200
#define KN 2000
#define VV 128
#define NGRU 8   // GRU blocks; each handles 8 batch rows

typedef __attribute__((ext_vector_type(8))) short bf16x8;
typedef __attribute__((ext_vector_type(4))) float f32x4;
typedef _Float16 half8 __attribute__((ext_vector_type(8)));

// ws layout (floats): pd[384]@0, pr[384]@384, uc[128]@768, ud[128]@896, ur[128]@1024

// r11/r13 lesson: IEEE divides were the gate chain; rcp forms (~1ulp) are fine.
__device__ __forceinline__ float sigm(float x) {
    return __builtin_amdgcn_rcpf(1.f + __expf(-x));
}
__device__ __forceinline__ float tanh_f(float x) {
    float e = __expf(2.f * x);
    return 1.f - 2.f * __builtin_amdgcn_rcpf(e + 1.f);
}

// lgkmcnt-only barrier: orders LDS produce->consume without draining in-flight
// global stores. sched_barrier keeps MFMA from hoisting past the wait (rule 18).
__device__ __forceinline__ void soft_barrier() {
    asm volatile("s_waitcnt lgkmcnt(0)" ::: "memory");
    __builtin_amdgcn_s_barrier();
    __builtin_amdgcn_sched_barrier(0);
}

// ---------------- precompute: small projection vectors ----------
__global__ void pre_kernel(const float* __restrict__ v_d, const float* __restrict__ v_r,
                           const float* __restrict__ v_c, const float* __restrict__ W_ih,
                           const float* __restrict__ W2a, float* __restrict__ ws)
{
    int g = blockIdx.x * 256 + threadIdx.x;   // grid 2 x 256 = 512 threads
    float* pd = ws;
    float* pr = ws + 384;
    float* uc = ws + 768;
    float* ud = ws + 896;
    float* ur = ws + 1024;
    if (g < 384) {
        float a = 0.f, b = 0.f;
        for (int k = 0; k < VV; ++k) {
            a = fmaf(W_ih[g * 256 + k], v_d[k], a);
            b = fmaf(W_ih[g * 256 + VV + k], v_r[k], b);
        }
        pd[g] = a; pr[g] = b;
    }
    if (g < VV) {
        float a = 0.f, b = 0.f, c = 0.f;
        for (int k = 0; k < VV; ++k) {
            a = fmaf(W2a[g * 384 + k], v_c[k], a);
            b = fmaf(W2a[g * 384 + VV + k], v_d[k], b);
            c = fmaf(W2a[g * 384 + 2 * VV + k], v_r[k], c);
        }
        uc[g] = a; ud[g] = b; ur[g] = c;
    }
}

__device__ __forceinline__ half8 load_cvt8h(const float* p) {
    float4 a = *(const float4*)p;
    float4 c = *(const float4*)(p + 4);
    half8 r;
    r[0] = (_Float16)a.x; r[1] = (_Float16)a.y; r[2] = (_Float16)a.z; r[3] = (_Float16)a.w;
    r[4] = (_Float16)c.x; r[5] = (_Float16)c.y; r[6] = (_Float16)c.z; r[7] = (_Float16)c.w;
    return r;
}

// ---------------- fused: blocks 0-7 GRU (8 rows each, MFMA), 8-71 mem scan ----
// r13 lesson: gate-phase trans issue (384 cy/SIMD/step) on only 4 CUs was the
// floor. Now 8 blocks x 8 batch rows, with rows placed at MFMA rows ≡{0,1}
// (mod 4): every lane's acc[0..1] is valid uniformly -> GATE runs exactly 2
// iterations, halving per-CU trans/VALU/MFMA issue. Lane gq owns batch rows
// 2gq, 2gq+1 of its block.
__global__ __launch_bounds__(512, 1) void fused_kernel(
    const int* __restrict__ c_seq, const int* __restrict__ d_seq,
    const float* __restrict__ r_seq, const float* __restrict__ D_emb,
    const float* __restrict__ Whh, const float* __restrict__ bih,
    const float* __restrict__ bhh, const float* __restrict__ W2b,
    const float* __restrict__ b2a, const float* __restrict__ b2b,
    const float* __restrict__ ws, float* __restrict__ C_out,
    float* __restrict__ h_out)
{
    __shared__ __align__(16) _Float16 H_half[16 * 136];   // MFMA rows; 2,3 mod 4 stay 0
    __shared__ __align__(8) float gam8[TT * 8], r8[TT * 8];  // [t][rr]
    __shared__ __align__(16) float C[KN];
    __shared__ float gam_row[TT], r_row[TT], n_row[TT];
    __shared__ int c_row[TT + 1];

    int tid = threadIdx.x;

    if (blockIdx.x < NGRU) {
        // ================= GRU path: 8 batch rows =================
        int b0 = blockIdx.x * 8;
        const float* pd = ws;
        const float* pr = ws + 384;

        for (int i = tid; i < TT * 8; i += 512) {
            int t = i >> 3, rr = i & 7;
            gam8[i] = D_emb[d_seq[(b0 + rr) * TT + t]];
            r8[i] = r_seq[(b0 + rr) * TT + t];
        }
        for (int i = tid; i < 16 * 136; i += 512) H_half[i] = (_Float16)0.f;

        int wid = tid >> 6, l = tid & 63;
        int cl = l & 15, gq = l >> 4;
        int nn = wid * 16 + cl;      // output col (0..127)
        // batch rows this lane owns: b0+2gq (acc[0], MFMA row gq*4) and
        // b0+2gq+1 (acc[1], MFMA row gq*4+1). acc[2..3] uniformly garbage.

        // B-fragments: 12 frags = 48 regs, resident (r9: FETCH 590KB confirmed)
        const float* wr = Whh + (size_t)nn * VV + gq * 8;
        const float* wz = Whh + (size_t)(nn + 128) * VV + gq * 8;
        const float* wn = Whh + (size_t)(nn + 256) * VV + gq * 8;
        half8 br0 = load_cvt8h(wr),      br1 = load_cvt8h(wr + 32),
              br2 = load_cvt8h(wr + 64), br3 = load_cvt8h(wr + 96);
        half8 bz0 = load_cvt8h(wz),      bz1 = load_cvt8h(wz + 32),
              bz2 = load_cvt8h(wz + 64), bz3 = load_cvt8h(wz + 96);
        half8 bn0 = load_cvt8h(wn),      bn1 = load_cvt8h(wn + 32),
              bn2 = load_cvt8h(wn + 64), bn3 = load_cvt8h(wn + 96);

        // per-lane gi fold scalars (col nn fixed per lane)
        float gr_pd = pd[nn],        gr_pr = pr[nn],        gr_b = bih[nn] + bhh[nn];
        float gz_pd = pd[nn + 128],  gz_pr = pr[nn + 128],  gz_b = bih[nn + 128] + bhh[nn + 128];
        float gn_pd = pd[nn + 256],  gn_pr = pr[nn + 256],  gn_b = bih[nn + 256];
        float gn_bh = bhh[nn + 256];

        float h0 = 0.f, h1 = 0.f;
        __syncthreads();   // setup barrier

        for (int t = 0; t < TT; ++t) {
            asm volatile("" : "+v"(br0), "+v"(br1), "+v"(br2), "+v"(br3),
                              "+v"(bz0), "+v"(bz1), "+v"(bz2), "+v"(bz3),
                              "+v"(bn0), "+v"(bn1), "+v"(bn2), "+v"(bn3));
            // A-fragments + per-step scalars (fold overlaps ds_read latency)
            const int ab = cl * 136 + gq * 8;
            half8 a0 = *(const half8*)&H_half[ab];
            half8 a1 = *(const half8*)&H_half[ab + 32];
            half8 a2 = *(const half8*)&H_half[ab + 64];
            half8 a3 = *(const half8*)&H_half[ab + 96];
            float2 g2 = *(const float2*)&gam8[t * 8 + 2 * gq];
            float2 q2 = *(const float2*)&r8[t * 8 + 2 * gq];

            // gi fold as MFMA C-in (only acc[0..1] meaningful)
            f32x4 accr = {0.f, 0.f, 0.f, 0.f};
            f32x4 accz = {0.f, 0.f, 0.f, 0.f};
            f32x4 accn = {0.f, 0.f, 0.f, 0.f};
            float gin0, gin1;
            accr[0] = fmaf(g2.x, gr_pd, fmaf(q2.x, gr_pr, gr_b));
            accr[1] = fmaf(g2.y, gr_pd, fmaf(q2.y, gr_pr, gr_b));
            accz[0] = fmaf(g2.x, gz_pd, fmaf(q2.x, gz_pr, gz_b));
            accz[1] = fmaf(g2.y, gz_pd, fmaf(q2.y, gz_pr, gz_b));
            accn[0] = gn_bh; accn[1] = gn_bh;
            gin0 = fmaf(g2.x, gn_pd, fmaf(q2.x, gn_pr, gn_b));
            gin1 = fmaf(g2.y, gn_pd, fmaf(q2.y, gn_pr, gn_b));

            accr = __builtin_amdgcn_mfma_f32_16x16x32_f16(a0, br0, accr, 0, 0, 0);
            accr = __builtin_amdgcn_mfma_f32_16x16x32_f16(a1, br1, accr, 0, 0, 0);
            accr = __builtin_amdgcn_mfma_f32_16x16x32_f16(a2, br2, accr, 0, 0, 0);
            accr = __builtin_amdgcn_mfma_f32_16x16x32_f16(a3, br3, accr, 0, 0, 0);
            accz = __builtin_amdgcn_mfma_f32_16x16x32_f16(a0, bz0, accz, 0, 0, 0);
            accz = __builtin_amdgcn_mfma_f32_16x16x32_f16(a1, bz1, accz, 0, 0, 0);
            accz = __builtin_amdgcn_mfma_f32_16x16x32_f16(a2, bz2, accz, 0, 0, 0);
            accz = __builtin_amdgcn_mfma_f32_16x16x32_f16(a3, bz3, accz, 0, 0, 0);
            accn = __builtin_amdgcn_mfma_f32_16x16x32_f16(a0, bn0, accn, 0, 0, 0);
            accn = __builtin_amdgcn_mfma_f32_16x16x32_f16(a1, bn1, accn, 0, 0, 0);
            accn = __builtin_amdgcn_mfma_f32_16x16x32_f16(a2, bn2, accn, 0, 0, 0);
            accn = __builtin_amdgcn_mfma_f32_16x16x32_f16(a3, bn3, accn, 0, 0, 0);

            // gates: acc[i] (i=0,1) = (batch row b0+2gq+i, col nn), lane-local
            {
                float rg0 = sigm(accr[0]);
                float zg0 = sigm(accz[0]);
                float ng0 = tanh_f(fmaf(rg0, accn[0], gin0));
                h0 = fmaf(1.f - zg0, ng0, zg0 * h0);
                float rg1 = sigm(accr[1]);
                float zg1 = sigm(accz[1]);
                float ng1 = tanh_f(fmaf(rg1, accn[1], gin1));
                h1 = fmaf(1.f - zg1, ng1, zg1 * h1);
                h_out[((size_t)(b0 + 2 * gq) * TT + t) * VV + nn] = h0;
                h_out[((size_t)(b0 + 2 * gq + 1) * TT + t) * VV + nn] = h1;
                H_half[(gq * 4) * 136 + nn] = (_Float16)h0;
                H_half[(gq * 4 + 1) * 136 + nn] = (_Float16)h1;
            }
            soft_barrier();   // LDS H_half visibility; h_out stays in flight
        }
    } else {
        // ================= memory-scan path: 2 phases =================
        int b = blockIdx.x - NGRU;
        const float* uc = ws + 768;
        const float* ud = ws + 896;
        const float* ur = ws + 1024;
        for (int i = tid; i < KN; i += 512) C[i] = 0.f;
        if (tid < TT) {
            gam_row[tid] = D_emb[d_seq[b * TT + tid]];
            r_row[tid] = r_seq[b * TT + tid];
            c_row[tid] = c_seq[b * TT + tid];
        }
        if (tid == 0) c_row[TT] = 0;
        __syncthreads();

        // ---- phase 1: wave0 scans; C[c(t+1)] prefetch + select breaks the
        //      dependent-LDS-read chain ----
        if (tid < 64) {
            int l = tid;
            float uc0 = uc[l], uc1 = uc[l + 64];
            float ud0 = ud[l], ud1 = ud[l + 64];
            float ur0 = ur[l], ur1 = ur[l + 64];
            float ba0 = b2a[l], ba1 = b2a[l + 64];
            float wb0 = W2b[l], wb1 = W2b[l + 64];
            float bb = b2b[0];
            float beta = 0.f;              // C starts all-zero
            int ct = c_row[0];
            for (int t = 0; t < TT; ++t) {
                int ct1 = c_row[t + 1];
                float cpref = C[ct1];      // early, independent issue
                float g = gam_row[t], rr = r_row[t];
                float hh0 = fmaxf(fmaf(beta, uc0, fmaf(g, ud0, fmaf(rr, ur0, ba0))), 0.f);
                float hh1 = fmaxf(fmaf(beta, uc1, fmaf(g, ud1, fmaf(rr, ur1, ba1))), 0.f);
                float p = fmaf(hh0, wb0, hh1 * wb1);
                #pragma unroll
                for (int m = 32; m > 0; m >>= 1) p += __shfl_xor(p, m);
                float nc = p + bb;
                if (l == 0) { C[ct] = nc; n_row[t] = nc; }
                beta = (ct1 == ct) ? nc : cpref;
                ct = ct1;
            }
        }
        __syncthreads();

        // ---- phase 2: all 8 waves reconstruct C_out; uniform-broadcast LDS
        //      reads, coalesced float4 stores, no barriers ----
        int k0 = tid * 4;
        if (k0 < KN) {
            float4 cur = {0.f, 0.f, 0.f, 0.f};
            float* cop = C_out + (size_t)b * TT * KN + k0;
            for (int t = 0; t < TT; ++t) {
                int c = c_row[t];
                unsigned d = (unsigned)(c - k0);
                if (d < 4u) {
                    float v = n_row[t];
                    cur.x = (d == 0u) ? v : cur.x;
                    cur.y = (d == 1u) ? v : cur.y;
                    cur.z = (d == 2u) ? v : cur.z;
                    cur.w = (d == 3u) ? v : cur.w;
                }
                *(float4*)(cop + (size_t)t * KN) = cur;
            }
        }
    }
}

// ---------------- alpha head: bf16 MFMA, fragments loaded straight from global -
__device__ __forceinline__ short f2bf(float f) {
    uint32_t u = __float_as_uint(f);
    u = (u + 0x7FFFu + ((u >> 16) & 1u)) >> 16;
    return (short)u;
}
__device__ __forceinline__ bf16x8 load_cvt8(const float* p) {
    float4 a = *(const float4*)p;
    float4 c = *(const float4*)(p + 4);
    bf16x8 r;
    r[0] = f2bf(a.x); r[1] = f2bf(a.y); r[2] = f2bf(a.z); r[3] = f2bf(a.w);
    r[4] = f2bf(c.x); r[5] = f2bf(c.y); r[6] = f2bf(c.z); r[7] = f2bf(c.w);
    return r;
}

__global__ void alpha_kernel(const float* __restrict__ h_seq, const float* __restrict__ W1a,
                             const float* __restrict__ b1a, const float* __restrict__ W1b,
                             const float* __restrict__ b1b, float* __restrict__ alpha)
{
    int wave = threadIdx.x >> 6;
    int lane = threadIdx.x & 63;
    int tile = blockIdx.x * 4 + wave;  // 800 tiles of 16 rows
    int rowbase = tile * 16;
    int rl = lane & 15, g = lane >> 4;
    const float* hp = h_seq + (size_t)(rowbase + rl) * VV + g * 8;
    bf16x8 a0 = load_cvt8(hp);
    bf16x8 a1 = load_cvt8(hp + 32);
    bf16x8 a2 = load_cvt8(hp + 64);
    bf16x8 a3 = load_cvt8(hp + 96);
    float p0 = 0.f, p1 = 0.f, p2 = 0.f, p3 = 0.f;
    float bb = b1b[0];
    #pragma unroll
    for (int jt = 0; jt < 8; ++jt) {
        int j = jt * 16 + rl;
        const float* wp = W1a + (size_t)j * VV + g * 8;
        f32x4 acc = {0.f, 0.f, 0.f, 0.f};
        acc = __builtin_amdgcn_mfma_f32_16x16x32_bf16(a0, load_cvt8(wp), acc, 0, 0, 0);
        acc = __builtin_amdgcn_mfma_f32_16x16x32_bf16(a1, load_cvt8(wp + 32), acc, 0, 0, 0);
        acc = __builtin_amdgcn_mfma_f32_16x16x32_bf16(a2, load_cvt8(wp + 64), acc, 0, 0, 0);
        acc = __builtin_amdgcn_mfma_f32_16x16x32_bf16(a3, load_cvt8(wp + 96), acc, 0, 0, 0);
        float bj = b1a[j], wj = W1b[j];
        p0 += fmaxf(acc[0] + bj, 0.f) * wj;
        p1 += fmaxf(acc[1] + bj, 0.f) * wj;
        p2 += fmaxf(acc[2] + bj, 0.f) * wj;
        p3 += fmaxf(acc[3] + bj, 0.f) * wj;
    }
    #pragma unroll
    for (int m = 1; m < 16; m <<= 1) {
        p0 += __shfl_xor(p0, m);
        p1 += __shfl_xor(p1, m);
        p2 += __shfl_xor(p2, m);
        p3 += __shfl_xor(p3, m);
    }
    if (rl == 0) {
        alpha[rowbase + g * 4 + 0] = p0 + bb;
        alpha[rowbase + g * 4 + 1] = p1 + bb;
        alpha[rowbase + g * 4 + 2] = p2 + bb;
        alpha[rowbase + g * 4 + 3] = p3 + bb;
    }
}

extern "C" void kernel_launch(void* const* d_in, const int* in_sizes, int n_in,
                              void* d_out, int out_size, void* d_ws, size_t ws_size,
                              hipStream_t stream)
{
    const int*   c_seq = (const int*)d_in[0];
    const int*   d_seq = (const int*)d_in[1];
    const float* r_seq = (const float*)d_in[2];
    const float* D_emb = (const float*)d_in[3];
    const float* v_d   = (const float*)d_in[4];
    const float* v_r   = (const float*)d_in[5];
    const float* v_c   = (const float*)d_in[6];
    const float* W_ih  = (const float*)d_in[7];
    const float* W_hh  = (const float*)d_in[8];
    const float* b_ih  = (const float*)d_in[9];
    const float* b_hh  = (const float*)d_in[10];
    const float* W1a   = (const float*)d_in[11];
    const float* b1a   = (const float*)d_in[12];
    const float* W1b   = (const float*)d_in[13];
    const float* b1b   = (const float*)d_in[14];
    const float* W2a   = (const float*)d_in[15];
    const float* b2a   = (const float*)d_in[16];
    const float* W2b   = (const float*)d_in[17];
    const float* b2b   = (const float*)d_in[18];

    float* out   = (float*)d_out;
    float* alpha = out;                       // 12800
    float* h_seq = out + 12800;               // 1,638,400
    float* C_out = out + 12800 + 1638400;     // 25,600,000
    float* ws    = (float*)d_ws;

    hipLaunchKernelGGL(pre_kernel, dim3(2), dim3(256), 0, stream,
                       v_d, v_r, v_c, W_ih, W2a, ws);
    hipLaunchKernelGGL(fused_kernel, dim3(NGRU + BB), dim3(512), 0, stream,
                       c_seq, d_seq, r_seq, D_emb, W_hh, b_ih, b_hh,
                       W2b, b2a, b2b, ws, C_out, h_seq);
    hipLaunchKernelGGL(alpha_kernel, dim3(200), dim3(256), 0, stream,
                       h_seq, W1a, b1a, W1b, b1b, alpha);
}

// Round 16
// 120.837 us; speedup vs baseline: 2.1766x; 1.1817x over previous
//
#include <hip/hip_runtime.h>
#include <hip/hip_bf16.h>
#include <cstdint>

#define BB 64
#define TT 200
#define KN 2000
#define VV 128
#define NGRU 16   // GRU blocks; each handles 4 batch rows

typedef __attribute__((ext_vector_type(8))) short bf16x8;
typedef __attribute__((ext_vector_type(4))) float f32x4;
typedef _Float16 half8 __attribute__((ext_vector_type(8)));

// ws layout (floats): pd[384]@0, pr[384]@384, uc[128]@768, ud[128]@896, ur[128]@1024

// r11/r13 lesson: IEEE divides were the gate chain; rcp forms (~1ulp) are fine.
__device__ __forceinline__ float sigm(float x) {
    return __builtin_amdgcn_rcpf(1.f + __expf(-x));
}
__device__ __forceinline__ float tanh_f(float x) {
    float e = __expf(2.f * x);
    return 1.f - 2.f * __builtin_amdgcn_rcpf(e + 1.f);
}

// lgkmcnt-only barrier: orders LDS produce->consume without draining in-flight
// global stores. sched_barrier keeps MFMA from hoisting past the wait (rule 18).
__device__ __forceinline__ void soft_barrier() {
    asm volatile("s_waitcnt lgkmcnt(0)" ::: "memory");
    __builtin_amdgcn_s_barrier();
    __builtin_amdgcn_sched_barrier(0);
}

// ---------------- precompute: small projection vectors ----------
__global__ void pre_kernel(const float* __restrict__ v_d, const float* __restrict__ v_r,
                           const float* __restrict__ v_c, const float* __restrict__ W_ih,
                           const float* __restrict__ W2a, float* __restrict__ ws)
{
    int g = blockIdx.x * 256 + threadIdx.x;   // grid 2 x 256 = 512 threads
    float* pd = ws;
    float* pr = ws + 384;
    float* uc = ws + 768;
    float* ud = ws + 896;
    float* ur = ws + 1024;
    if (g < 384) {
        float a = 0.f, b = 0.f;
        for (int k = 0; k < VV; ++k) {
            a = fmaf(W_ih[g * 256 + k], v_d[k], a);
            b = fmaf(W_ih[g * 256 + VV + k], v_r[k], b);
        }
        pd[g] = a; pr[g] = b;
    }
    if (g < VV) {
        float a = 0.f, b = 0.f, c = 0.f;
        for (int k = 0; k < VV; ++k) {
            a = fmaf(W2a[g * 384 + k], v_c[k], a);
            b = fmaf(W2a[g * 384 + VV + k], v_d[k], b);
            c = fmaf(W2a[g * 384 + 2 * VV + k], v_r[k], c);
        }
        uc[g] = a; ud[g] = b; ur[g] = c;
    }
}

__device__ __forceinline__ half8 load_cvt8h(const float* p) {
    float4 a = *(const float4*)p;
    float4 c = *(const float4*)(p + 4);
    half8 r;
    r[0] = (_Float16)a.x; r[1] = (_Float16)a.y; r[2] = (_Float16)a.z; r[3] = (_Float16)a.w;
    r[4] = (_Float16)c.x; r[5] = (_Float16)c.y; r[6] = (_Float16)c.z; r[7] = (_Float16)c.w;
    return r;
}

// ---------------- fused: blocks 0-15 GRU (4 rows each, MFMA), 16-79 mem scan --
// r15 lesson: 8 blocks x 2-row gates cut fused 144->107; still ~50% latency-
// exposed. Now 16 blocks x 4 batch rows placed at MFMA rows ≡0 (mod 4): lane
// gq's acc[0] is the single valid row -> GATE = 1 row (6 trans), halving
// per-CU trans/gate-VALU issue again, spread over 16 CUs.
__global__ __launch_bounds__(512, 1) void fused_kernel(
    const int* __restrict__ c_seq, const int* __restrict__ d_seq,
    const float* __restrict__ r_seq, const float* __restrict__ D_emb,
    const float* __restrict__ Whh, const float* __restrict__ bih,
    const float* __restrict__ bhh, const float* __restrict__ W2b,
    const float* __restrict__ b2a, const float* __restrict__ b2b,
    const float* __restrict__ ws, float* __restrict__ C_out,
    float* __restrict__ h_out)
{
    __shared__ __align__(16) _Float16 H_half[16 * 136];   // rows ≢0 mod 4 stay 0
    __shared__ __align__(8) float gam4[TT * 4], r4[TT * 4];  // [t][rr]
    __shared__ __align__(16) float C[KN];
    __shared__ float gam_row[TT], r_row[TT], n_row[TT];
    __shared__ int c_row[TT + 1];

    int tid = threadIdx.x;

    if (blockIdx.x < NGRU) {
        // ================= GRU path: 4 batch rows =================
        int b0 = blockIdx.x * 4;
        const float* pd = ws;
        const float* pr = ws + 384;

        for (int i = tid; i < TT * 4; i += 512) {
            int t = i >> 2, rr = i & 3;
            gam4[i] = D_emb[d_seq[(b0 + rr) * TT + t]];
            r4[i] = r_seq[(b0 + rr) * TT + t];
        }
        for (int i = tid; i < 16 * 136; i += 512) H_half[i] = (_Float16)0.f;

        int wid = tid >> 6, l = tid & 63;
        int cl = l & 15, gq = l >> 4;
        int nn = wid * 16 + cl;      // output col (0..127)
        // batch row this lane owns: b0+gq, at MFMA row gq*4 (acc[0]).
        // acc[1..3] uniformly garbage.

        // B-fragments: 12 frags = 48 regs, resident (r9: FETCH 590KB confirmed)
        const float* wr = Whh + (size_t)nn * VV + gq * 8;
        const float* wz = Whh + (size_t)(nn + 128) * VV + gq * 8;
        const float* wn = Whh + (size_t)(nn + 256) * VV + gq * 8;
        half8 br0 = load_cvt8h(wr),      br1 = load_cvt8h(wr + 32),
              br2 = load_cvt8h(wr + 64), br3 = load_cvt8h(wr + 96);
        half8 bz0 = load_cvt8h(wz),      bz1 = load_cvt8h(wz + 32),
              bz2 = load_cvt8h(wz + 64), bz3 = load_cvt8h(wz + 96);
        half8 bn0 = load_cvt8h(wn),      bn1 = load_cvt8h(wn + 32),
              bn2 = load_cvt8h(wn + 64), bn3 = load_cvt8h(wn + 96);

        // per-lane gi fold scalars (col nn fixed per lane)
        float gr_pd = pd[nn],        gr_pr = pr[nn],        gr_b = bih[nn] + bhh[nn];
        float gz_pd = pd[nn + 128],  gz_pr = pr[nn + 128],  gz_b = bih[nn + 128] + bhh[nn + 128];
        float gn_pd = pd[nn + 256],  gn_pr = pr[nn + 256],  gn_b = bih[nn + 256];
        float gn_bh = bhh[nn + 256];

        float h0 = 0.f;
        __syncthreads();   // setup barrier

        for (int t = 0; t < TT; ++t) {
            asm volatile("" : "+v"(br0), "+v"(br1), "+v"(br2), "+v"(br3),
                              "+v"(bz0), "+v"(bz1), "+v"(bz2), "+v"(bz3),
                              "+v"(bn0), "+v"(bn1), "+v"(bn2), "+v"(bn3));
            // A-fragments + per-step scalars (fold overlaps ds_read latency)
            const int ab = cl * 136 + gq * 8;
            half8 a0 = *(const half8*)&H_half[ab];
            half8 a1 = *(const half8*)&H_half[ab + 32];
            half8 a2 = *(const half8*)&H_half[ab + 64];
            half8 a3 = *(const half8*)&H_half[ab + 96];
            float g1 = gam4[t * 4 + gq];
            float q1 = r4[t * 4 + gq];

            // gi fold as MFMA C-in (only acc[0] meaningful)
            f32x4 accr = {0.f, 0.f, 0.f, 0.f};
            f32x4 accz = {0.f, 0.f, 0.f, 0.f};
            f32x4 accn = {0.f, 0.f, 0.f, 0.f};
            accr[0] = fmaf(g1, gr_pd, fmaf(q1, gr_pr, gr_b));
            accz[0] = fmaf(g1, gz_pd, fmaf(q1, gz_pr, gz_b));
            accn[0] = gn_bh;
            float gin0 = fmaf(g1, gn_pd, fmaf(q1, gn_pr, gn_b));

            accr = __builtin_amdgcn_mfma_f32_16x16x32_f16(a0, br0, accr, 0, 0, 0);
            accr = __builtin_amdgcn_mfma_f32_16x16x32_f16(a1, br1, accr, 0, 0, 0);
            accr = __builtin_amdgcn_mfma_f32_16x16x32_f16(a2, br2, accr, 0, 0, 0);
            accr = __builtin_amdgcn_mfma_f32_16x16x32_f16(a3, br3, accr, 0, 0, 0);
            accz = __builtin_amdgcn_mfma_f32_16x16x32_f16(a0, bz0, accz, 0, 0, 0);
            accz = __builtin_amdgcn_mfma_f32_16x16x32_f16(a1, bz1, accz, 0, 0, 0);
            accz = __builtin_amdgcn_mfma_f32_16x16x32_f16(a2, bz2, accz, 0, 0, 0);
            accz = __builtin_amdgcn_mfma_f32_16x16x32_f16(a3, bz3, accz, 0, 0, 0);
            accn = __builtin_amdgcn_mfma_f32_16x16x32_f16(a0, bn0, accn, 0, 0, 0);
            accn = __builtin_amdgcn_mfma_f32_16x16x32_f16(a1, bn1, accn, 0, 0, 0);
            accn = __builtin_amdgcn_mfma_f32_16x16x32_f16(a2, bn2, accn, 0, 0, 0);
            accn = __builtin_amdgcn_mfma_f32_16x16x32_f16(a3, bn3, accn, 0, 0, 0);

            // gate: acc[0] = (batch row b0+gq, col nn), lane-local
            {
                float rg0 = sigm(accr[0]);
                float zg0 = sigm(accz[0]);
                float ng0 = tanh_f(fmaf(rg0, accn[0], gin0));
                h0 = fmaf(1.f - zg0, ng0, zg0 * h0);
                h_out[((size_t)(b0 + gq) * TT + t) * VV + nn] = h0;
                H_half[(gq * 4) * 136 + nn] = (_Float16)h0;
            }
            soft_barrier();   // LDS H_half visibility; h_out stays in flight
        }
    } else {
        // ================= memory-scan path: 2 phases =================
        int b = blockIdx.x - NGRU;
        const float* uc = ws + 768;
        const float* ud = ws + 896;
        const float* ur = ws + 1024;
        for (int i = tid; i < KN; i += 512) C[i] = 0.f;
        if (tid < TT) {
            gam_row[tid] = D_emb[d_seq[b * TT + tid]];
            r_row[tid] = r_seq[b * TT + tid];
            c_row[tid] = c_seq[b * TT + tid];
        }
        if (tid == 0) c_row[TT] = 0;
        __syncthreads();

        // ---- phase 1: wave0 scans; C[c(t+1)] prefetch + select breaks the
        //      dependent-LDS-read chain ----
        if (tid < 64) {
            int l = tid;
            float uc0 = uc[l], uc1 = uc[l + 64];
            float ud0 = ud[l], ud1 = ud[l + 64];
            float ur0 = ur[l], ur1 = ur[l + 64];
            float ba0 = b2a[l], ba1 = b2a[l + 64];
            float wb0 = W2b[l], wb1 = W2b[l + 64];
            float bb = b2b[0];
            float beta = 0.f;              // C starts all-zero
            int ct = c_row[0];
            for (int t = 0; t < TT; ++t) {
                int ct1 = c_row[t + 1];
                float cpref = C[ct1];      // early, independent issue
                float g = gam_row[t], rr = r_row[t];
                float hh0 = fmaxf(fmaf(beta, uc0, fmaf(g, ud0, fmaf(rr, ur0, ba0))), 0.f);
                float hh1 = fmaxf(fmaf(beta, uc1, fmaf(g, ud1, fmaf(rr, ur1, ba1))), 0.f);
                float p = fmaf(hh0, wb0, hh1 * wb1);
                #pragma unroll
                for (int m = 32; m > 0; m >>= 1) p += __shfl_xor(p, m);
                float nc = p + bb;
                if (l == 0) { C[ct] = nc; n_row[t] = nc; }
                beta = (ct1 == ct) ? nc : cpref;
                ct = ct1;
            }
        }
        __syncthreads();

        // ---- phase 2: all 8 waves reconstruct C_out; uniform-broadcast LDS
        //      reads, coalesced float4 stores, no barriers ----
        int k0 = tid * 4;
        if (k0 < KN) {
            float4 cur = {0.f, 0.f, 0.f, 0.f};
            float* cop = C_out + (size_t)b * TT * KN + k0;
            for (int t = 0; t < TT; ++t) {
                int c = c_row[t];
                unsigned d = (unsigned)(c - k0);
                if (d < 4u) {
                    float v = n_row[t];
                    cur.x = (d == 0u) ? v : cur.x;
                    cur.y = (d == 1u) ? v : cur.y;
                    cur.z = (d == 2u) ? v : cur.z;
                    cur.w = (d == 3u) ? v : cur.w;
                }
                *(float4*)(cop + (size_t)t * KN) = cur;
            }
        }
    }
}

// ---------------- alpha head: bf16 MFMA, fragments loaded straight from global -
__device__ __forceinline__ short f2bf(float f) {
    uint32_t u = __float_as_uint(f);
    u = (u + 0x7FFFu + ((u >> 16) & 1u)) >> 16;
    return (short)u;
}
__device__ __forceinline__ bf16x8 load_cvt8(const float* p) {
    float4 a = *(const float4*)p;
    float4 c = *(const float4*)(p + 4);
    bf16x8 r;
    r[0] = f2bf(a.x); r[1] = f2bf(a.y); r[2] = f2bf(a.z); r[3] = f2bf(a.w);
    r[4] = f2bf(c.x); r[5] = f2bf(c.y); r[6] = f2bf(c.z); r[7] = f2bf(c.w);
    return r;
}

__global__ void alpha_kernel(const float* __restrict__ h_seq, const float* __restrict__ W1a,
                             const float* __restrict__ b1a, const float* __restrict__ W1b,
                             const float* __restrict__ b1b, float* __restrict__ alpha)
{
    int wave = threadIdx.x >> 6;
    int lane = threadIdx.x & 63;
    int tile = blockIdx.x * 4 + wave;  // 800 tiles of 16 rows
    int rowbase = tile * 16;
    int rl = lane & 15, g = lane >> 4;
    const float* hp = h_seq + (size_t)(rowbase + rl) * VV + g * 8;
    bf16x8 a0 = load_cvt8(hp);
    bf16x8 a1 = load_cvt8(hp + 32);
    bf16x8 a2 = load_cvt8(hp + 64);
    bf16x8 a3 = load_cvt8(hp + 96);
    float p0 = 0.f, p1 = 0.f, p2 = 0.f, p3 = 0.f;
    float bb = b1b[0];
    #pragma unroll
    for (int jt = 0; jt < 8; ++jt) {
        int j = jt * 16 + rl;
        const float* wp = W1a + (size_t)j * VV + g * 8;
        f32x4 acc = {0.f, 0.f, 0.f, 0.f};
        acc = __builtin_amdgcn_mfma_f32_16x16x32_bf16(a0, load_cvt8(wp), acc, 0, 0, 0);
        acc = __builtin_amdgcn_mfma_f32_16x16x32_bf16(a1, load_cvt8(wp + 32), acc, 0, 0, 0);
        acc = __builtin_amdgcn_mfma_f32_16x16x32_bf16(a2, load_cvt8(wp + 64), acc, 0, 0, 0);
        acc = __builtin_amdgcn_mfma_f32_16x16x32_bf16(a3, load_cvt8(wp + 96), acc, 0, 0, 0);
        float bj = b1a[j], wj = W1b[j];
        p0 += fmaxf(acc[0] + bj, 0.f) * wj;
        p1 += fmaxf(acc[1] + bj, 0.f) * wj;
        p2 += fmaxf(acc[2] + bj, 0.f) * wj;
        p3 += fmaxf(acc[3] + bj, 0.f) * wj;
    }
    #pragma unroll
    for (int m = 1; m < 16; m <<= 1) {
        p0 += __shfl_xor(p0, m);
        p1 += __shfl_xor(p1, m);
        p2 += __shfl_xor(p2, m);
        p3 += __shfl_xor(p3, m);
    }
    if (rl == 0) {
        alpha[rowbase + g * 4 + 0] = p0 + bb;
        alpha[rowbase + g * 4 + 1] = p1 + bb;
        alpha[rowbase + g * 4 + 2] = p2 + bb;
        alpha[rowbase + g * 4 + 3] = p3 + bb;
    }
}

extern "C" void kernel_launch(void* const* d_in, const int* in_sizes, int n_in,
                              void* d_out, int out_size, void* d_ws, size_t ws_size,
                              hipStream_t stream)
{
    const int*   c_seq = (const int*)d_in[0];
    const int*   d_seq = (const int*)d_in[1];
    const float* r_seq = (const float*)d_in[2];
    const float* D_emb = (const float*)d_in[3];
    const float* v_d   = (const float*)d_in[4];
    const float* v_r   = (const float*)d_in[5];
    const float* v_c   = (const float*)d_in[6];
    const float* W_ih  = (const float*)d_in[7];
    const float* W_hh  = (const float*)d_in[8];
    const float* b_ih  = (const float*)d_in[9];
    const float* b_hh  = (const float*)d_in[10];
    const float* W1a   = (const float*)d_in[11];
    const float* b1a   = (const float*)d_in[12];
    const float* W1b   = (const float*)d_in[13];
    const float* b1b   = (const float*)d_in[14];
    const float* W2a   = (const float*)d_in[15];
    const float* b2a   = (const float*)d_in[16];
    const float* W2b   = (const float*)d_in[17];
    const float* b2b   = (const float*)d_in[18];

    float* out   = (float*)d_out;
    float* alpha = out;                       // 12800
    float* h_seq = out + 12800;               // 1,638,400
    float* C_out = out + 12800 + 1638400;     // 25,600,000
    float* ws    = (float*)d_ws;

    hipLaunchKernelGGL(pre_kernel, dim3(2), dim3(256), 0, stream,
                       v_d, v_r, v_c, W_ih, W2a, ws);
    hipLaunchKernelGGL(fused_kernel, dim3(NGRU + BB), dim3(512), 0, stream,
                       c_seq, d_seq, r_seq, D_emb, W_hh, b_ih, b_hh,
                       W2b, b2a, b2b, ws, C_out, h_seq);
    hipLaunchKernelGGL(alpha_kernel, dim3(200), dim3(256), 0, stream,
                       h_seq, W1a, b1a, W1b, b1b, alpha);
}